// Round 4
// baseline (2207.995 us; speedup 1.0000x reference)
//
#include <hip/hip_runtime.h>
#include <cstdint>
#include <cstddef>

// ---------------------------------------------------------------------------
// LSTM forward, persistent-kernel design (round 4): TAGGED-H protocol.
//   grid = 256 WGs = 4 batch-groups(16 rows) x 64 hidden-groups(16 cols)
//   h element = one dword: (bf16(h)<<16) | (t+1).  Consumers poll the DATA
//   (sc0|sc1 dwordx4) until all low-16 tags == t: discovery == data load,
//   no flag store, no relay, no separate h-load trip. Parity double-slab
//   keeps step t / t+2 writes from colliding (same proof as flag version).
//   ALL 8 waves now split BOTH K-halves: per wave 128 x-cols + 128 h-cols.
//   x-MFMA (L2-cached, dependency-free) runs between the tagged store and
//   the poll -> hides producers' store-to-IC latency.
//   LDS: 8x4 partial C tiles (16x16 fp32, padded col stride) -> fused epilogue
//   c-state lives in thread registers across all 512 steps.
// ---------------------------------------------------------------------------

typedef short bf16x8 __attribute__((ext_vector_type(8)));
typedef float f32x4  __attribute__((ext_vector_type(4)));
typedef int   i32x4  __attribute__((ext_vector_type(4)));

#define XT_OFF   0ull                 // x^T bf16 [512][64][1024]  = 64 MiB
#define WT_OFF   67108864ull          // W^T bf16 [4096][2048]     = 16 MiB
#define HB_OFF   83886080ull          // tagged h dbuf uint [2][64][1024] = 512 KiB
#define WS_NEED  84410368ull

__device__ __forceinline__ unsigned short f2bf(float f) {
  union { float f; unsigned u; } v; v.f = f;
  unsigned r = (v.u + 0x7fffu + ((v.u >> 16) & 1u)) >> 16;   // RNE
  return (unsigned short)r;
}

// x (B,S,I) fp32 -> xT (S,B,I) bf16.  blk = b*512+s, 256 thr x float4
__global__ void k_convert_x(const float* __restrict__ x, unsigned short* __restrict__ xT) {
  const int blk = blockIdx.x;
  const int b = blk >> 9, s = blk & 511;
  const float4 v = ((const float4*)(x + (size_t)blk * 1024))[threadIdx.x];
  ushort4 o;
  o.x = f2bf(v.x); o.y = f2bf(v.y); o.z = f2bf(v.z); o.w = f2bf(v.w);
  ((ushort4*)(xT + ((size_t)s * 64 + b) * 1024))[threadIdx.x] = o;
}

// W [2048][4096] fp32 -> WT [4096][2048] bf16, 64x64 LDS tiles
__global__ void k_convert_W(const float* __restrict__ W, unsigned short* __restrict__ WT) {
  __shared__ float tile[64][65];
  const int bx = blockIdx.x & 31;   // k-tile
  const int by = blockIdx.x >> 5;   // g-tile
  const int k0 = bx << 6, g0 = by << 6;
  for (int i = threadIdx.x; i < 4096; i += 256) {
    const int r = i >> 6, c = i & 63;
    tile[r][c] = W[(size_t)(k0 + r) * 4096 + g0 + c];
  }
  __syncthreads();
  for (int i = threadIdx.x; i < 4096; i += 256) {
    const int g = i >> 6, k = i & 63;
    WT[(size_t)(g0 + g) * 2048 + k0 + k] = f2bf(tile[k][g]);
  }
}

// zero both tagged-h slabs (tags -> 0 == valid h(0)=0 for step 0)
__global__ void k_init(unsigned int* __restrict__ hbuf) {
  const size_t i = (size_t)blockIdx.x * 256 + threadIdx.x;
  ((uint4*)hbuf)[i] = uint4{0u, 0u, 0u, 0u};    // 128 blk x 256 thr x 16B = 512 KiB
}

__global__ __launch_bounds__(512, 1) void lstm_persistent(
    const unsigned short* __restrict__ xT,   // [512][64][1024] bf16
    const unsigned short* __restrict__ WT,   // [4096][2048] bf16
    const float* __restrict__ bias,          // [4096]
    unsigned int* __restrict__ hbuf,         // [2][64][1024] tagged dwords
    float* __restrict__ out)                 // outputs(B,S,H) + h_T + c_T
{
  __shared__ float slots[8 * 4 * 320];       // [wave][gate][col*20 + row], 40 KiB

  const int tid  = threadIdx.x;
  const int lane = tid & 63;
  const int wave = tid >> 6;                 // 0..7: 128 x-cols + 128 h-cols each
  const int bg = blockIdx.x & 3;             // batch group (16 rows)
  const int hg = blockIdx.x >> 2;            // hidden group (16 cols)
  const int b0 = bg << 4;
  const int l15 = lane & 15;
  const int l4  = lane >> 4;

  // --- loop-invariant B fragments: 4 gates x (4 x-chunks + 4 h-chunks) ---
  bf16x8 Bf[4][8];
#pragma unroll
  for (int g = 0; g < 4; ++g) {
    const unsigned short* wr =
        WT + (size_t)(g * 1024 + (hg << 4) + l15) * 2048 + l4 * 8;
#pragma unroll
    for (int kc = 0; kc < 4; ++kc)
      Bf[g][kc] = *(const bf16x8*)(wr + wave * 128 + kc * 32);          // x side
#pragma unroll
    for (int kc = 0; kc < 4; ++kc)
      Bf[g][4 + kc] = *(const bf16x8*)(wr + 1024 + wave * 128 + kc * 32); // h side
  }

  // --- per-cell epilogue constants (threads 0..255: cell (row rb, col cc)) ---
  const int cc = tid & 15;
  const int rb = (tid >> 4) & 15;
  float bi = 0.f, bff = 0.f, bgg = 0.f, bo = 0.f;
  if (tid < 256) {
    const int col = (hg << 4) + cc;
    bi  = bias[col];
    bff = bias[1024 + col];
    bgg = bias[2048 + col];
    bo  = bias[3072 + col];
  }
  float c_state = 0.f;
  bool dead = false;                         // latched poll guard; fail fast, no hang

  const unsigned short* xb = xT + (size_t)(b0 + l15) * 1024 + wave * 128 + l4 * 8;
  const unsigned int*   hp = hbuf + (size_t)(b0 + l15) * 1024 + wave * 128 + l4 * 8;
  unsigned int* hw = hbuf + (size_t)(b0 + rb) * 1024 + (hg << 4) + cc;
  float* outp = out + (size_t)(b0 + rb) * 512 * 1024 + (hg << 4) + cc;
  float* sb = &slots[(wave * 4) * 320 + l15 * 20 + l4 * 4];

  i32x4 R[8];                                // raw tagged h (persists across steps)

#pragma unroll 1
  for (int t = 0; t < 512; ++t) {
    const int par = t & 1;

    // ---- x-part: 4 chunks from L2-cached xT (no cross-WG dependency).
    //      Runs between last step's tagged store and this step's poll ->
    //      covers producers' store-to-IC latency.
    f32x4 a0 = {0.f, 0.f, 0.f, 0.f};
    f32x4 a1 = a0, a2 = a0, a3 = a0;
    {
      const unsigned short* xp = xb + (size_t)t * 65536;
      bf16x8 Ax[4];
#pragma unroll
      for (int kc = 0; kc < 4; ++kc) Ax[kc] = *(const bf16x8*)(xp + kc * 32);
#pragma unroll
      for (int kc = 0; kc < 4; ++kc) {
        a0 = __builtin_amdgcn_mfma_f32_16x16x32_bf16(Ax[kc], Bf[0][kc], a0, 0, 0, 0);
        a1 = __builtin_amdgcn_mfma_f32_16x16x32_bf16(Ax[kc], Bf[1][kc], a1, 0, 0, 0);
        a2 = __builtin_amdgcn_mfma_f32_16x16x32_bf16(Ax[kc], Bf[2][kc], a2, 0, 0, 0);
        a3 = __builtin_amdgcn_mfma_f32_16x16x32_bf16(Ax[kc], Bf[3][kc], a3, 0, 0, 0);
      }
    }

    // ---- h-part: poll tagged data until all 32 tags == t, then MFMA ----
    {
      const unsigned int* hq = hp + (size_t)par * 65536;
      const unsigned tgt = (unsigned)t;
      if (!dead) {
        long guard = 0;
        for (;;) {
#pragma unroll
          for (int c = 0; c < 4; ++c) {
            asm volatile("global_load_dwordx4 %0, %1, off sc0 sc1"
                         : "=v"(R[2 * c]) : "v"(hq + c * 32) : "memory");
            asm volatile("global_load_dwordx4 %0, %1, off sc0 sc1"
                         : "=v"(R[2 * c + 1]) : "v"(hq + c * 32 + 4) : "memory");
          }
          asm volatile("s_waitcnt vmcnt(0)"
                       : "+v"(R[0]), "+v"(R[1]), "+v"(R[2]), "+v"(R[3]),
                         "+v"(R[4]), "+v"(R[5]), "+v"(R[6]), "+v"(R[7])
                       :: "memory");
          unsigned acc = 0u;
#pragma unroll
          for (int r = 0; r < 8; ++r) {
            acc |= ((unsigned)R[r][0] ^ tgt);
            acc |= ((unsigned)R[r][1] ^ tgt);
            acc |= ((unsigned)R[r][2] ^ tgt);
            acc |= ((unsigned)R[r][3] ^ tgt);
          }
          if (__all((int)((acc & 0xFFFFu) == 0u))) break;
          if (++guard > (1l << 18)) { dead = true; break; }  // fail fast
        }
      }
      // repack hi-16 halves -> bf16x8 fragments, accumulate h-part
#pragma unroll
      for (int c = 0; c < 4; ++c) {
        union { i32x4 i; bf16x8 h; } Ah;
        Ah.i[0] = (int)__builtin_amdgcn_perm((unsigned)R[2*c][1],   (unsigned)R[2*c][0],   0x07060302u);
        Ah.i[1] = (int)__builtin_amdgcn_perm((unsigned)R[2*c][3],   (unsigned)R[2*c][2],   0x07060302u);
        Ah.i[2] = (int)__builtin_amdgcn_perm((unsigned)R[2*c+1][1], (unsigned)R[2*c+1][0], 0x07060302u);
        Ah.i[3] = (int)__builtin_amdgcn_perm((unsigned)R[2*c+1][3], (unsigned)R[2*c+1][2], 0x07060302u);
        a0 = __builtin_amdgcn_mfma_f32_16x16x32_bf16(Ah.h, Bf[0][4 + c], a0, 0, 0, 0);
        a1 = __builtin_amdgcn_mfma_f32_16x16x32_bf16(Ah.h, Bf[1][4 + c], a1, 0, 0, 0);
        a2 = __builtin_amdgcn_mfma_f32_16x16x32_bf16(Ah.h, Bf[2][4 + c], a2, 0, 0, 0);
        a3 = __builtin_amdgcn_mfma_f32_16x16x32_bf16(Ah.h, Bf[3][4 + c], a3, 0, 0, 0);
      }
    }

    *(f32x4*)(sb + 0)   = a0;
    *(f32x4*)(sb + 320) = a1;
    *(f32x4*)(sb + 640) = a2;
    *(f32x4*)(sb + 960) = a3;
    __syncthreads();   // partials complete

    float hval = 0.f;
    if (tid < 256) {
      float Gi = bi, Gf = bff, Gg = bgg, Go = bo;
      const int base = cc * 20 + rb;
#pragma unroll
      for (int w = 0; w < 8; ++w) {
        Gi += slots[(w * 4 + 0) * 320 + base];
        Gf += slots[(w * 4 + 1) * 320 + base];
        Gg += slots[(w * 4 + 2) * 320 + base];
        Go += slots[(w * 4 + 3) * 320 + base];
      }
      const float ig = 1.f / (1.f + __expf(-Gi));
      const float fg = 1.f / (1.f + __expf(-Gf));
      const float og = 1.f / (1.f + __expf(-Go));
      float ag = __builtin_fabsf(Gg);
      float eg = __expf(-2.f * ag);
      float tg = (1.f - eg) / (1.f + eg);
      tg = (Gg < 0.f) ? -tg : tg;
      c_state = fg * c_state + ig * tg;
      float ac = __builtin_fabsf(c_state);
      float ec = __expf(-2.f * ac);
      float tc = (1.f - ec) / (1.f + ec);
      tc = (c_state < 0.f) ? -tc : tc;
      hval = og * tc;
      // tagged h(t+1) -> other parity slab; tag t+1 self-announces at IC
      unsigned tagged = ((unsigned)f2bf(hval) << 16) | (unsigned)(t + 1);
      asm volatile("global_store_dword %0, %1, off sc0 sc1"
                   :: "v"(hw + (size_t)(par ^ 1) * 65536), "v"(tagged) : "memory");
    }
    __syncthreads();   // h stores drained (vmcnt(0) before s_barrier) + slots consumed

    if (tid < 256) {
      outp[(size_t)t * 1024] = hval;              // off critical path
      if (t == 511) {
        const size_t o2 = 33554432ull + (size_t)(b0 + rb) * 1024 + (hg << 4) + cc;
        out[o2] = hval;                           // h_T
        out[o2 + 65536] = c_state;                // c_T
      }
    }
  }
}

extern "C" void kernel_launch(void* const* d_in, const int* in_sizes, int n_in,
                              void* d_out, int out_size, void* d_ws, size_t ws_size,
                              hipStream_t stream) {
  const float* x = (const float*)d_in[0];   // (64,512,1024)
  const float* W = (const float*)d_in[1];   // (2048,4096)
  const float* b = (const float*)d_in[2];   // (4096,)
  float* out = (float*)d_out;
  char* ws = (char*)d_ws;
  if (ws_size < WS_NEED) return;            // need ~84.4 MB scratch

  unsigned short* xT = (unsigned short*)(ws + XT_OFF);
  unsigned short* WT = (unsigned short*)(ws + WT_OFF);
  unsigned int*   hb = (unsigned int*)(ws + HB_OFF);

  hipLaunchKernelGGL(k_convert_x, dim3(32768), dim3(256), 0, stream, x, xT);
  hipLaunchKernelGGL(k_convert_W, dim3(2048),  dim3(256), 0, stream, W, WT);
  hipLaunchKernelGGL(k_init,      dim3(128),   dim3(256), 0, stream, hb);

  // Launch-path hedge: cooperative launch skipped under stream capture,
  // plain-launch fallback on any error. Grid = 1 WG/CU x 256 CUs either way.
  void* kargs[] = { (void*)&xT, (void*)&WT, (void*)&b, (void*)&hb, (void*)&out };
  hipStreamCaptureStatus cap = hipStreamCaptureStatusNone;
  (void)hipStreamIsCapturing(stream, &cap);
  hipError_t lerr = hipErrorUnknown;
  if (cap == hipStreamCaptureStatusNone) {
    lerr = hipLaunchCooperativeKernel((void*)lstm_persistent, dim3(256), dim3(512),
                                      kargs, 0, stream);
  }
  if (lerr != hipSuccess) {
    hipLaunchKernelGGL(lstm_persistent, dim3(256), dim3(512), 0, stream,
                       xT, WT, b, hb, out);
  }
}

// Round 5
// 1859.455 us; speedup vs baseline: 1.1874x; 1.1874x over previous
//
#include <hip/hip_runtime.h>
#include <cstdint>
#include <cstddef>

// ---------------------------------------------------------------------------
// LSTM forward, persistent-kernel design (round 5):
//   grid = 256 WGs = 4 batch-groups(16 rows) x 64 hidden-groups(16 cols)
//   Revert to round-3 NARROW-FLAG protocol (round-4 tagged-h regressed:
//   wide-data polling cost IC bandwidth). Refinements:
//     - ALL 8 waves split BOTH K-halves (128 x-cols + 128 h-cols each):
//       post-discovery critical path halves (4KB load + 16 MFMA per wave).
//     - FINE-GRAINED flags: wave w polls exactly the 8 producer flags of its
//       own h K-slice (no relay, no go_flag). Late producers stall only the
//       wave that needs them; ready chunks load/compute under the wait.
//   Cross-WG h + flags stay sc0|sc1 cache-BYPASS (coherent at IC, no fences).
//   LDS: 8x4 partial C tiles (16x16 fp32, padded col stride) -> fused epilogue
//   c-state lives in thread registers across all 512 steps.
// ---------------------------------------------------------------------------

typedef short bf16x8 __attribute__((ext_vector_type(8)));
typedef float f32x4  __attribute__((ext_vector_type(4)));
typedef int   i32x4  __attribute__((ext_vector_type(4)));

#define XT_OFF   0ull                 // x^T bf16 [512][64][1024]  = 64 MiB
#define WT_OFF   67108864ull          // W^T bf16 [4096][2048]     = 16 MiB
#define HB_OFF   83886080ull          // h double buffer bf16 [2][64][1024] = 256 KiB
#define CNT_OFF  84148224ull          // 256 flags, 256B-spaced = 64 KiB
#define WS_NEED  84213760ull

__device__ __forceinline__ unsigned short f2bf(float f) {
  union { float f; unsigned u; } v; v.f = f;
  unsigned r = (v.u + 0x7fffu + ((v.u >> 16) & 1u)) >> 16;   // RNE
  return (unsigned short)r;
}

// x (B,S,I) fp32 -> xT (S,B,I) bf16.  blk = b*512+s, 256 thr x float4
__global__ void k_convert_x(const float* __restrict__ x, unsigned short* __restrict__ xT) {
  const int blk = blockIdx.x;
  const int b = blk >> 9, s = blk & 511;
  const float4 v = ((const float4*)(x + (size_t)blk * 1024))[threadIdx.x];
  ushort4 o;
  o.x = f2bf(v.x); o.y = f2bf(v.y); o.z = f2bf(v.z); o.w = f2bf(v.w);
  ((ushort4*)(xT + ((size_t)s * 64 + b) * 1024))[threadIdx.x] = o;
}

// W [2048][4096] fp32 -> WT [4096][2048] bf16, 64x64 LDS tiles
__global__ void k_convert_W(const float* __restrict__ W, unsigned short* __restrict__ WT) {
  __shared__ float tile[64][65];
  const int bx = blockIdx.x & 31;   // k-tile
  const int by = blockIdx.x >> 5;   // g-tile
  const int k0 = bx << 6, g0 = by << 6;
  for (int i = threadIdx.x; i < 4096; i += 256) {
    const int r = i >> 6, c = i & 63;
    tile[r][c] = W[(size_t)(k0 + r) * 4096 + g0 + c];
  }
  __syncthreads();
  for (int i = threadIdx.x; i < 4096; i += 256) {
    const int g = i >> 6, k = i & 63;
    WT[(size_t)(g0 + g) * 2048 + k0 + k] = f2bf(tile[k][g]);
  }
}

// zero h parity-0 slab (131072 B) + 64 KiB of flags
__global__ void k_init(unsigned short* __restrict__ hbuf, unsigned int* __restrict__ cnt) {
  const size_t i = (size_t)blockIdx.x * 256 + threadIdx.x;
  ((uint4*)hbuf)[i] = uint4{0u, 0u, 0u, 0u};
  ((uint2*)cnt)[i]  = uint2{0u, 0u};          // 8192 thr x 8B = 64 KiB
}

__global__ __launch_bounds__(512, 1) void lstm_persistent(
    const unsigned short* __restrict__ xT,   // [512][64][1024] bf16
    const unsigned short* __restrict__ WT,   // [4096][2048] bf16
    const float* __restrict__ bias,          // [4096]
    unsigned short* __restrict__ hbuf,       // [2][64][1024] bf16
    unsigned int* __restrict__ cnt,          // 256 flags, 64-uint (256B) stride
    float* __restrict__ out)                 // outputs(B,S,H) + h_T + c_T
{
  __shared__ float slots[8 * 4 * 320];       // [wave][gate][col*20 + row], 40 KiB

  const int tid  = threadIdx.x;
  const int lane = tid & 63;
  const int wave = tid >> 6;                 // 0..7: 128 x-cols + 128 h-cols each
  const int bg = blockIdx.x & 3;             // batch group (16 rows)
  const int hg = blockIdx.x >> 2;            // hidden group (16 cols)
  const int b0 = bg << 4;
  const int l15 = lane & 15;
  const int l4  = lane >> 4;

  // --- loop-invariant B fragments: 4 gates x (4 x-chunks + 4 h-chunks) ---
  bf16x8 Bf[4][8];
#pragma unroll
  for (int g = 0; g < 4; ++g) {
    const unsigned short* wp =
        WT + (size_t)(g * 1024 + (hg << 4) + l15) * 2048 + l4 * 8;
#pragma unroll
    for (int kc = 0; kc < 4; ++kc)
      Bf[g][kc] = *(const bf16x8*)(wp + wave * 128 + kc * 32);            // x side
#pragma unroll
    for (int kc = 0; kc < 4; ++kc)
      Bf[g][4 + kc] = *(const bf16x8*)(wp + 1024 + wave * 128 + kc * 32); // h side
  }

  // --- per-cell epilogue constants (threads 0..255: cell (row rb, col cc)) ---
  const int cc = tid & 15;
  const int rb = (tid >> 4) & 15;
  float bi = 0.f, bff = 0.f, bgg = 0.f, bo = 0.f;
  if (tid < 256) {
    const int col = (hg << 4) + cc;
    bi  = bias[col];
    bff = bias[1024 + col];
    bgg = bias[2048 + col];
    bo  = bias[3072 + col];
  }
  float c_state = 0.f;
  bool dead = false;                         // latched poll guard; fail fast, no hang

  // flags: publisher (one per WG) / per-wave poll set (8 producers of my slice)
  unsigned int* myFlag   = cnt + (size_t)((bg << 6) | hg) * 64;
  const unsigned int* fp = cnt + (size_t)((bg << 6) | (wave << 3) | (lane & 7)) * 64;

  const unsigned short* xb = xT + (size_t)(b0 + l15) * 1024 + wave * 128 + l4 * 8;
  const unsigned short* hp = hbuf + (size_t)(b0 + l15) * 1024 + wave * 128 + l4 * 8;
  unsigned short* hw = hbuf + (size_t)(b0 + rb) * 1024 + (hg << 4) + cc;
  float* outp = out + (size_t)(b0 + rb) * 512 * 1024 + (hg << 4) + cc;
  float* sb = &slots[(wave * 4) * 320 + l15 * 20 + l4 * 4];

#pragma unroll 1
  for (int t = 0; t < 512; ++t) {
    const int par = t & 1;
    f32x4 a0 = {0.f, 0.f, 0.f, 0.f};
    f32x4 a1 = a0, a2 = a0, a3 = a0;

    // ---- x-part: 4 chunks from L2-cached xT (no cross-WG dependency).
    //      Runs between last step's flag publish and this step's poll ->
    //      covers producers' store-to-IC latency.
    {
      const unsigned short* xp = xb + (size_t)t * 65536;
      bf16x8 Ax[4];
#pragma unroll
      for (int kc = 0; kc < 4; ++kc) Ax[kc] = *(const bf16x8*)(xp + kc * 32);
#pragma unroll
      for (int kc = 0; kc < 4; ++kc) {
        a0 = __builtin_amdgcn_mfma_f32_16x16x32_bf16(Ax[kc], Bf[0][kc], a0, 0, 0, 0);
        a1 = __builtin_amdgcn_mfma_f32_16x16x32_bf16(Ax[kc], Bf[1][kc], a1, 0, 0, 0);
        a2 = __builtin_amdgcn_mfma_f32_16x16x32_bf16(Ax[kc], Bf[2][kc], a2, 0, 0, 0);
        a3 = __builtin_amdgcn_mfma_f32_16x16x32_bf16(Ax[kc], Bf[3][kc], a3, 0, 0, 0);
      }
    }

    // ---- fine-grained flag poll: this wave's 8 producers only ----
    if (t > 0 && !dead) {
      const unsigned int tgt = (unsigned int)t;
      long guard = 0;
      for (;;) {
        unsigned int v;
        asm volatile("global_load_dword %0, %1, off sc0 sc1"
                     : "=v"(v) : "v"(fp) : "memory");
        asm volatile("s_waitcnt vmcnt(0)" : "+v"(v) :: "memory");
        if (__all((int)(v >= tgt))) break;
        if (++guard > (1l << 18)) { dead = true; break; }  // fail fast
      }
    }

    // ---- h-part: one-shot bypass load of my 4KB slice, then 16 MFMA ----
    {
      const unsigned short* hq = hp + (size_t)par * 65536;
      union { i32x4 i; bf16x8 h; } Ah[4];
#pragma unroll
      for (int kc = 0; kc < 4; ++kc) {
        asm volatile("global_load_dwordx4 %0, %1, off sc0 sc1"
                     : "=v"(Ah[kc].i) : "v"(hq + kc * 32) : "memory");
      }
      asm volatile("s_waitcnt vmcnt(0)"
                   : "+v"(Ah[0].i), "+v"(Ah[1].i), "+v"(Ah[2].i), "+v"(Ah[3].i)
                   :: "memory");
#pragma unroll
      for (int kc = 0; kc < 4; ++kc) {
        a0 = __builtin_amdgcn_mfma_f32_16x16x32_bf16(Ah[kc].h, Bf[0][4 + kc], a0, 0, 0, 0);
        a1 = __builtin_amdgcn_mfma_f32_16x16x32_bf16(Ah[kc].h, Bf[1][4 + kc], a1, 0, 0, 0);
        a2 = __builtin_amdgcn_mfma_f32_16x16x32_bf16(Ah[kc].h, Bf[2][4 + kc], a2, 0, 0, 0);
        a3 = __builtin_amdgcn_mfma_f32_16x16x32_bf16(Ah[kc].h, Bf[3][4 + kc], a3, 0, 0, 0);
      }
    }

    *(f32x4*)(sb + 0)   = a0;
    *(f32x4*)(sb + 320) = a1;
    *(f32x4*)(sb + 640) = a2;
    *(f32x4*)(sb + 960) = a3;
    __syncthreads();   // partials complete

    float hval = 0.f;
    if (tid < 256) {
      float Gi = bi, Gf = bff, Gg = bgg, Go = bo;
      const int base = cc * 20 + rb;
#pragma unroll
      for (int w = 0; w < 8; ++w) {
        Gi += slots[(w * 4 + 0) * 320 + base];
        Gf += slots[(w * 4 + 1) * 320 + base];
        Gg += slots[(w * 4 + 2) * 320 + base];
        Go += slots[(w * 4 + 3) * 320 + base];
      }
      const float ig = 1.f / (1.f + __expf(-Gi));
      const float fg = 1.f / (1.f + __expf(-Gf));
      const float og = 1.f / (1.f + __expf(-Go));
      float ag = __builtin_fabsf(Gg);
      float eg = __expf(-2.f * ag);
      float tg = (1.f - eg) / (1.f + eg);
      tg = (Gg < 0.f) ? -tg : tg;
      c_state = fg * c_state + ig * tg;
      float ac = __builtin_fabsf(c_state);
      float ec = __expf(-2.f * ac);
      float tc = (1.f - ec) / (1.f + ec);
      tc = (c_state < 0.f) ? -tc : tc;
      hval = og * tc;
      // h(t+1) -> other parity slab, cache-bypass (visible at IC; no fence)
      unsigned int hbits = (unsigned int)f2bf(hval);
      asm volatile("global_store_short %0, %1, off sc0 sc1"
                   :: "v"(hw + (size_t)(par ^ 1) * 65536), "v"(hbits) : "memory");
    }
    __syncthreads();   // h stores drained (vmcnt(0) before s_barrier) + slots consumed

    if (tid == 0) {
      // single-writer publish: h(t+1) is at IC for this WG -> flag = t+1
      asm volatile("global_store_dword %0, %1, off sc0 sc1"
                   :: "v"(myFlag), "v"((unsigned int)(t + 1)) : "memory");
    }
    if (tid < 256) {
      outp[(size_t)t * 1024] = hval;              // off critical path
      if (t == 511) {
        const size_t o2 = 33554432ull + (size_t)(b0 + rb) * 1024 + (hg << 4) + cc;
        out[o2] = hval;                           // h_T
        out[o2 + 65536] = c_state;                // c_T
      }
    }
  }
}

extern "C" void kernel_launch(void* const* d_in, const int* in_sizes, int n_in,
                              void* d_out, int out_size, void* d_ws, size_t ws_size,
                              hipStream_t stream) {
  const float* x = (const float*)d_in[0];   // (64,512,1024)
  const float* W = (const float*)d_in[1];   // (2048,4096)
  const float* b = (const float*)d_in[2];   // (4096,)
  float* out = (float*)d_out;
  char* ws = (char*)d_ws;
  if (ws_size < WS_NEED) return;            // need ~84.3 MB scratch

  unsigned short* xT = (unsigned short*)(ws + XT_OFF);
  unsigned short* WT = (unsigned short*)(ws + WT_OFF);
  unsigned short* hb = (unsigned short*)(ws + HB_OFF);
  unsigned int*  cn = (unsigned int*)(ws + CNT_OFF);

  hipLaunchKernelGGL(k_convert_x, dim3(32768), dim3(256), 0, stream, x, xT);
  hipLaunchKernelGGL(k_convert_W, dim3(2048),  dim3(256), 0, stream, W, WT);
  hipLaunchKernelGGL(k_init,      dim3(32),    dim3(256), 0, stream, hb, cn);

  // Launch-path hedge: cooperative launch skipped under stream capture,
  // plain-launch fallback on any error. Grid = 1 WG/CU x 256 CUs either way.
  void* kargs[] = { (void*)&xT, (void*)&WT, (void*)&b, (void*)&hb, (void*)&cn, (void*)&out };
  hipStreamCaptureStatus cap = hipStreamCaptureStatusNone;
  (void)hipStreamIsCapturing(stream, &cap);
  hipError_t lerr = hipErrorUnknown;
  if (cap == hipStreamCaptureStatusNone) {
    lerr = hipLaunchCooperativeKernel((void*)lstm_persistent, dim3(256), dim3(512),
                                      kargs, 0, stream);
  }
  if (lerr != hipSuccess) {
    hipLaunchKernelGGL(lstm_persistent, dim3(256), dim3(512), 0, stream,
                       xT, WT, b, hb, cn, out);
  }
}